// Round 6
// baseline (79.766 us; speedup 1.0000x reference)
//
#include <hip/hip_runtime.h>
#include <hip/hip_bf16.h>
#include <math.h>

#define B_ 4
#define I_ 48
#define J_ 384
#define DT_ 512
#define DM_ 80
#define DA_ 128
#define WIDTH_ 338          // J - I + 2
#define NEG (-1e30f)
#define LOG2E 1.4426950408889634f
#define LN2 0.6931471805599453f
#define LOGEPS2 (-1442.6950408889634f)   // -1000 * log2(e)
#define VPT 6               // positions per lane in the single-wave DP

typedef float f32x4 __attribute__((ext_vector_type(4)));
typedef float f32x2 __attribute__((ext_vector_type(2)));

__device__ __forceinline__ float fexp2(float x) { return __builtin_amdgcn_exp2f(x); }
__device__ __forceinline__ float flog2(float x) { return __builtin_amdgcn_logf(x); }  // log2!

// DPP fetch with NEG fill (identity for LSE). 0x138=wave_shr:1 (lane t <- t-1),
// 0x130=wave_shl:1 (lane t <- t+1). Validated R3/R4.
template<int CTRL, int RMASK>
__device__ __forceinline__ float dppf(float x) {
    return __int_as_float(__builtin_amdgcn_update_dpp(
        __float_as_int(NEG), __float_as_int(x), CTRL, RMASK, 0xF, false));
}
__device__ __forceinline__ float rlane(float x, int l) {
    return __int_as_float(__builtin_amdgcn_readlane(__float_as_int(x), l));
}

// Branch-free LSE in log2 domain. NEG acts as -inf (exp2 flushes to 0).
__device__ __forceinline__ float lse2(float a, float b) {
    float m = fmaxf(a, b);
    float d = a - b;
    return m + flog2(1.0f + fexp2(-fabsf(d)));
}
__device__ __forceinline__ float lse4(float a, float b, float c, float d) {
    float m = fmaxf(fmaxf(a, b), fmaxf(c, d));
    float s = fexp2(a - m) + fexp2(b - m) + fexp2(c - m) + fexp2(d - m);
    return m + flog2(s);
}

// 64-lane inclusive forward LSE-scan, DPP only.
__device__ __forceinline__ float wave_scan_fwd(float x) {
    x = lse2(x, dppf<0x111, 0xF>(x));   // row_shr:1
    x = lse2(x, dppf<0x112, 0xF>(x));   // row_shr:2
    x = lse2(x, dppf<0x114, 0xF>(x));   // row_shr:4
    x = lse2(x, dppf<0x118, 0xF>(x));   // row_shr:8
    x = lse2(x, dppf<0x142, 0xA>(x));   // row_bcast15 -> rows 1,3
    x = lse2(x, dppf<0x143, 0xC>(x));   // row_bcast31 -> rows 2,3
    return x;
}
// 64-lane inclusive reverse (suffix) LSE-scan.
__device__ __forceinline__ float wave_scan_rev(float x, int lane) {
    x = lse2(x, dppf<0x101, 0xF>(x));   // row_shl:1
    x = lse2(x, dppf<0x102, 0xF>(x));
    x = lse2(x, dppf<0x104, 0xF>(x));
    x = lse2(x, dppf<0x108, 0xF>(x));
    float s16 = rlane(x, 16), s32 = rlane(x, 32), s48 = rlane(x, 48);
    float a  = lse2(s32, s48);
    float b2 = lse2(s16, a);
    int row = lane >> 4;
    float pre = (row == 0) ? b2 : (row == 1) ? a : (row == 2) ? s48 : NEG;
    return lse2(x, pre);
}

// fast tanh via hardware exp2
__device__ __forceinline__ float tanh_fast(float x) {
    x = fminf(fmaxf(x, -15.f), 15.f);
    float t = fexp2(x * (2.0f * LOG2E));
    return __fdividef(t - 1.0f, t + 1.0f);
}

// ---------------- K1: projections pt = text@Wt ; pm = mel@Wm + bm ----------
__global__ __launch_bounds__(128) void proj_kernel(
        const float* __restrict__ text, const float* __restrict__ mel,
        const float* __restrict__ Wt, const float* __restrict__ Wm,
        const float* __restrict__ bm, float* __restrict__ pt, float* __restrict__ pm) {
    int blk = blockIdx.x;
    int d = threadIdx.x;
    __shared__ float sx[DT_];
    if (blk < B_ * I_) {
        const float* x = text + blk * DT_;
        for (int e = d; e < DT_; e += DA_) sx[e] = x[e];
        __syncthreads();
        float acc = 0.f;
        #pragma unroll 8
        for (int e = 0; e < DT_; ++e) acc += sx[e] * Wt[e * DA_ + d];
        pt[blk * DA_ + d] = acc;
    } else {
        int r = blk - B_ * I_;
        const float* x = mel + r * DM_;
        if (d < DM_) sx[d] = x[d];
        __syncthreads();
        float acc = bm[d];
        #pragma unroll 8
        for (int e = 0; e < DM_; ++e) acc += sx[e] * Wm[e * DA_ + d];
        pm[r * DA_ + d] = acc;
    }
}

// ---------------- K2: energy + rev-cum -> interleaved EZ[b,i][2j]={E,Z} ----
__global__ __launch_bounds__(384) void energy_kernel(
        const float* __restrict__ pt, const float* __restrict__ pm,
        const float* __restrict__ vw, const float* __restrict__ vb,
        const float* __restrict__ noise, float* __restrict__ EZ) {
    int bi = blockIdx.x;            // b*I + i
    int b = bi / I_, i = bi % I_;
    int t = threadIdx.x;            // j
    int w = t >> 6, lane = t & 63;
    __shared__ float sPt[DA_];
    __shared__ float sPR[8];
    __shared__ float sLast;
    if (t < DA_) sPt[t] = pt[bi * DA_ + t];
    __syncthreads();
    const float4* pmr4 = (const float4*)(pm + (size_t)(b * J_ + t) * DA_);
    float acc = 0.f;
    #pragma unroll 8
    for (int q = 0; q < DA_ / 4; ++q) {
        float4 v = pmr4[q];
        acc += vw[4 * q + 0] * tanh_fast(sPt[4 * q + 0] + v.x);
        acc += vw[4 * q + 1] * tanh_fast(sPt[4 * q + 1] + v.y);
        acc += vw[4 * q + 2] * tanh_fast(sPt[4 * q + 2] + v.z);
        acc += vw[4 * q + 3] * tanh_fast(sPt[4 * q + 3] + v.w);
    }
    float e = (acc + vb[0] + 2.0f * noise[bi * J_ + t]) * LOG2E;   // log2 domain

    float y = wave_scan_rev(e, lane);
    if (lane == 0) sPR[w] = y;
    if (t == J_ - 1) sLast = e;
    __syncthreads();
    float preR = NEG;
    #pragma unroll
    for (int ww = 1; ww < 6; ++ww) if (ww > w) preR = lse2(preR, sPR[ww]);
    float z = lse2(y, preR);
    if (i == I_ - 1) z = sLast;     // last text row: only j=J-1 valid
    float2 o; o.x = e; o.y = z;
    ((float2*)(EZ + (size_t)bi * J_ * 2))[t] = o;
}

// ---------------- K3: banded DP — asm-owned distance-5 vmem pipeline -------
// Per iteration: exactly 3 asm loads (row r+5) + 3 asm stores (row r).
// Counted s_waitcnt vmcnt(N): steady N=27, prologue 12/15/18/21/24,
// tail 24/21/18/15 (ops newer than row r's loads; see derivation in session notes).
#define WAITV_(n) asm volatile("s_waitcnt vmcnt(" #n ")" ::: "memory")
#define WAITV(n) do { WAITV_(n); __builtin_amdgcn_sched_barrier(0); } while (0)

#define LOAD3(S, rowexpr) do { \
    const float* _a = EZb + (size_t)(rowexpr) * (2 * J_) + t * 12; \
    asm volatile("global_load_dwordx4 %0, %3, off\n\t" \
                 "global_load_dwordx4 %1, %3, off offset:16\n\t" \
                 "global_load_dwordx4 %2, %3, off offset:32" \
                 : "=&v"(S##0), "=&v"(S##1), "=&v"(S##2) \
                 : "v"(_a) : "memory"); } while (0)

#define STORE3(addr, x0, x1, x2) \
    asm volatile("global_store_dwordx2 %3, %0, off\n\t" \
                 "global_store_dwordx2 %3, %1, off offset:8\n\t" \
                 "global_store_dwordx2 %3, %2, off offset:16" \
                 :: "v"(x0), "v"(x1), "v"(x2), "v"(addr) : "memory")

#define BODY(iexpr, NW, S, DOLOAD, lrow) do { \
    const int i_ = (iexpr); \
    WAITV(NW); \
    float e_[VPT]  = {S##0[0], S##0[2], S##1[0], S##1[2], S##2[0], S##2[2]}; \
    float zz_[VPT] = {S##0[1], S##0[3], S##1[1], S##1[3], S##2[1], S##2[3]}; \
    float D[VPT]; \
    _Pragma("unroll") \
    for (int r = 0; r < VPT; ++r) D[r] = prev[r] - zz_[r]; \
    float f1  = lse2(D[0], D[1]); \
    float p23 = lse2(D[2], D[3]); \
    float p45 = lse2(D[4], D[5]); \
    float fS[VPT], g[VPT]; \
    fS[0] = D[0]; fS[1] = f1; \
    fS[2] = lse2(f1, D[2]);    fS[3] = lse2(f1, p23); \
    fS[4] = lse2(fS[3], D[4]); fS[5] = lse2(fS[3], p45); \
    g[5] = D[5]; g[4] = p45; \
    g[3] = lse2(D[3], p45);  g[2] = lse2(p23, p45); \
    g[1] = lse2(D[1], g[2]); g[0] = lse2(f1, g[2]); \
    float Sf  = wave_scan_fwd(fS[5]); \
    float exF = dppf<0x138, 0xF>(Sf); \
    float Sg  = wave_scan_rev(g[0], t); \
    float exG = dppf<0x130, 0xF>(Sg); \
    float ePrev = dppf<0x138, 0xF>(e_[VPT - 1]); \
    _Pragma("unroll") \
    for (int r = 0; r < VPT; ++r) { \
        int j = p0 + r; \
        float eL = (r == 0) ? ePrev : e_[r - 1]; \
        float fp = (r == 0) ? NEG   : fS[r - 1]; \
        float v = lse4(eL + fp, eL + exF, g[r] + LOGEPS2, exG + LOGEPS2); \
        prev[r] = (j >= i_ && j < i_ + WIDTH_) ? v : NEG; \
    } \
    if (DOLOAD) LOAD3(S, lrow); \
    { f32x2 pk0 = {prev[0], prev[1]}, pk1 = {prev[2], prev[3]}, pk2 = {prev[4], prev[5]}; \
      float* _ba = Bb + i_ * J_ + p0; \
      STORE3(_ba, pk0, pk1, pk2); } \
} while (0)

__global__ __launch_bounds__(64) void dp_kernel(
        const float* __restrict__ EZ, float* __restrict__ Bij) {
    int b = blockIdx.x;
    int t = threadIdx.x;            // 64 lanes, VPT=6 contiguous positions each
    int p0 = t * VPT;
    const float* EZb = EZ + (size_t)b * I_ * J_ * 2;
    float* Bb = Bij + b * I_ * J_;

    float prev[VPT];
    #pragma unroll
    for (int r = 0; r < VPT; ++r) prev[r] = (p0 + r == 0) ? 0.f : NEG;

    // row 0 of Bij (asm store: keeps per-iter vmem op counts exact)
    { f32x2 pk0 = {prev[0], prev[1]}, pk1 = {prev[2], prev[3]}, pk2 = {prev[4], prev[5]};
      float* _ba = Bb + p0;
      STORE3(_ba, pk0, pk1, pk2); }

    f32x4 SA0, SA1, SA2, SB0, SB1, SB2, SC0, SC1, SC2, SD0, SD1, SD2, SE0, SE1, SE2;
    LOAD3(SA, 0); LOAD3(SB, 1); LOAD3(SC, 2); LOAD3(SD, 3); LOAD3(SE, 4);

    BODY(1, 12, SA, 1, 5);
    BODY(2, 15, SB, 1, 6);
    BODY(3, 18, SC, 1, 7);
    BODY(4, 21, SD, 1, 8);
    BODY(5, 24, SE, 1, 9);
    for (int ib = 6; ib <= 36; ib += 5) {
        BODY(ib + 0, 27, SA, 1, ib + 4);
        BODY(ib + 1, 27, SB, 1, ib + 5);
        BODY(ib + 2, 27, SC, 1, ib + 6);
        BODY(ib + 3, 27, SD, 1, ib + 7);
        BODY(ib + 4, 27, SE, 1, ib + 8);
    }
    BODY(41, 27, SA, 1, 45);
    BODY(42, 27, SB, 1, 46);
    BODY(43, 27, SC, 0, 0);
    BODY(44, 24, SD, 0, 0);
    BODY(45, 21, SE, 0, 0);
    BODY(46, 18, SA, 0, 0);
    BODY(47, 15, SB, 0, 0);
}

// ---------------- K4: soft[b,i,j] — one barrier, register scans ------------
__global__ __launch_bounds__(384) void soft_kernel(
        const float* __restrict__ Bij, const float* __restrict__ EZ,
        float* __restrict__ soft) {
    int bi = blockIdx.x;
    int i = bi % I_;
    int t = threadIdx.x;
    int w = t >> 6, lane = t & 63;
    __shared__ float sPF[8], sPR[8];
    float bv = Bij[bi * J_ + t];
    float2 ez = ((const float2*)(EZ + (size_t)bi * J_ * 2))[t];
    float zz = ez.y;

    float xf = wave_scan_fwd(bv - zz);       // fwd scan of (B - ZZ)
    float yr = wave_scan_rev(bv, lane);      // rev scan of B
    if (lane == 63) sPF[w] = xf;
    if (lane == 0)  sPR[w] = yr;
    __syncthreads();
    float preF = NEG, preR = NEG;
    #pragma unroll
    for (int ww = 0; ww < 5; ++ww) if (ww < w) preF = lse2(preF, sPF[ww]);
    #pragma unroll
    for (int ww = 1; ww < 6; ++ww) if (ww > w) preR = lse2(preR, sPR[ww]);

    float v;
    if (i < I_ - 1) {
        float cum   = lse2(xf, preF);                       // LSE_{k<=j}(B-ZZ)
        float revp1 = lse2(dppf<0x130, 0xF>(yr), preR);     // LSE_{k>j}(B)
        v = lse2(zz + cum, revp1 + LOGEPS2);
    } else {
        float tot = lse2(lse2(lse2(sPR[0], sPR[1]), lse2(sPR[2], sPR[3])),
                         lse2(sPR[4], sPR[5]));             // LSE_k B[last,k]
        v = (t == J_ - 1) ? tot : tot + LOGEPS2;
    }
    soft[bi * J_ + t] = v * LN2;            // back to natural log
}

// ---------------- K5: expanded[b,j,d] = sum_i exp(soft[b,i,j]) * text[b,i,d]
__global__ __launch_bounds__(512) void expand_kernel(
        const float* __restrict__ soft, const float* __restrict__ text,
        float* __restrict__ out) {
    int bj = blockIdx.x;
    int b = bj / J_, j = bj % J_;
    int d = threadIdx.x;
    __shared__ float p[I_];
    if (d < I_) p[d] = __expf(soft[(b * I_ + d) * J_ + j]);
    __syncthreads();
    float acc = 0.f;
    #pragma unroll
    for (int i = 0; i < I_; ++i) acc += p[i] * text[(b * I_ + i) * DT_ + d];
    out[bj * DT_ + d] = acc;
}

extern "C" void kernel_launch(void* const* d_in, const int* in_sizes, int n_in,
                              void* d_out, int out_size, void* d_ws, size_t ws_size,
                              hipStream_t stream) {
    const float* text  = (const float*)d_in[0];
    const float* mel   = (const float*)d_in[1];
    const float* noise = (const float*)d_in[2];
    const float* Wt    = (const float*)d_in[3];
    const float* Wm    = (const float*)d_in[4];
    const float* bm    = (const float*)d_in[5];
    const float* vw    = (const float*)d_in[6];
    const float* vb    = (const float*)d_in[7];
    // masks (d_in[8], d_in[9]) are all-true in this problem: tlen=I, mlen=J hardcoded.

    float* ws  = (float*)d_ws;
    float* EZ  = ws;                         // B*I*J*2 (interleaved E,Z; 16B aligned)
    float* pt  = EZ + B_ * I_ * J_ * 2;      // B*I*DA
    float* pm  = pt + B_ * I_ * DA_;         // B*J*DA
    float* Bij = pm + B_ * J_ * DA_;         // B*I*J   (log2 domain)

    float* soft     = (float*)d_out;             // B*I*J   (natural log)
    float* expanded = soft + B_ * I_ * J_;       // B*J*DT

    proj_kernel<<<B_ * (I_ + J_), 128, 0, stream>>>(text, mel, Wt, Wm, bm, pt, pm);
    energy_kernel<<<B_ * I_, 384, 0, stream>>>(pt, pm, vw, vb, noise, EZ);
    dp_kernel<<<B_, 64, 0, stream>>>(EZ, Bij);
    soft_kernel<<<B_ * I_, 384, 0, stream>>>(Bij, EZ, soft);
    expand_kernel<<<B_ * J_, 512, 0, stream>>>(soft, text, expanded);
}

// Round 7
// 57.681 us; speedup vs baseline: 1.3829x; 1.3829x over previous
//
#include <hip/hip_runtime.h>
#include <hip/hip_bf16.h>
#include <math.h>

#define B_ 4
#define I_ 48
#define J_ 384
#define DT_ 512
#define DM_ 80
#define DA_ 128
#define WIDTH_ 338          // J - I + 2
#define NEG (-1e30f)
#define LOG2E 1.4426950408889634f
#define LN2 0.6931471805599453f
#define LOGEPS2 (-1442.6950408889634f)   // -1000 * log2(e)
#define VPT 6               // positions per lane in the single-wave DP

typedef float f32x4 __attribute__((ext_vector_type(4)));
typedef float f32x2 __attribute__((ext_vector_type(2)));

__device__ __forceinline__ float fexp2(float x) { return __builtin_amdgcn_exp2f(x); }
__device__ __forceinline__ float flog2(float x) { return __builtin_amdgcn_logf(x); }  // log2!

// DPP fetch with NEG fill (identity for LSE). 0x138=wave_shr:1 (lane t <- t-1),
// 0x130=wave_shl:1 (lane t <- t+1). Validated R3/R4/R5.
template<int CTRL, int RMASK>
__device__ __forceinline__ float dppf(float x) {
    return __int_as_float(__builtin_amdgcn_update_dpp(
        __float_as_int(NEG), __float_as_int(x), CTRL, RMASK, 0xF, false));
}
__device__ __forceinline__ float rlane(float x, int l) {
    return __int_as_float(__builtin_amdgcn_readlane(__float_as_int(x), l));
}

// Branch-free LSE in log2 domain. NEG acts as -inf (exp2 flushes to 0).
__device__ __forceinline__ float lse2(float a, float b) {
    float m = fmaxf(a, b);
    float d = a - b;
    return m + flog2(1.0f + fexp2(-fabsf(d)));
}

// 64-lane inclusive forward LSE-scan, DPP only.
__device__ __forceinline__ float wave_scan_fwd(float x) {
    x = lse2(x, dppf<0x111, 0xF>(x));   // row_shr:1
    x = lse2(x, dppf<0x112, 0xF>(x));   // row_shr:2
    x = lse2(x, dppf<0x114, 0xF>(x));   // row_shr:4
    x = lse2(x, dppf<0x118, 0xF>(x));   // row_shr:8
    x = lse2(x, dppf<0x142, 0xA>(x));   // row_bcast15 -> rows 1,3
    x = lse2(x, dppf<0x143, 0xC>(x));   // row_bcast31 -> rows 2,3
    return x;
}
// 64-lane inclusive reverse (suffix) LSE-scan.
__device__ __forceinline__ float wave_scan_rev(float x, int lane) {
    x = lse2(x, dppf<0x101, 0xF>(x));   // row_shl:1
    x = lse2(x, dppf<0x102, 0xF>(x));
    x = lse2(x, dppf<0x104, 0xF>(x));
    x = lse2(x, dppf<0x108, 0xF>(x));
    float s16 = rlane(x, 16), s32 = rlane(x, 32), s48 = rlane(x, 48);
    float a  = lse2(s32, s48);
    float b2 = lse2(s16, a);
    int row = lane >> 4;
    float pre = (row == 0) ? b2 : (row == 1) ? a : (row == 2) ? s48 : NEG;
    return lse2(x, pre);
}

// fast tanh: t = exp2(2x*log2e); tanh = 1 - 2/(t+1). Inf/0 limits correct.
__device__ __forceinline__ float tanh_fast(float x) {
    float t = fexp2(x * (2.0f * LOG2E));
    return fmaf(-2.0f, __builtin_amdgcn_rcpf(t + 1.0f), 1.0f);
}

// ---------------- K1: projections pt = text@Wt ; pm = mel@Wm + bm ----------
__global__ __launch_bounds__(128) void proj_kernel(
        const float* __restrict__ text, const float* __restrict__ mel,
        const float* __restrict__ Wt, const float* __restrict__ Wm,
        const float* __restrict__ bm, float* __restrict__ pt, float* __restrict__ pm) {
    int blk = blockIdx.x;
    int d = threadIdx.x;
    __shared__ float sx[DT_];
    if (blk < B_ * I_) {
        const float* x = text + blk * DT_;
        for (int e = d; e < DT_; e += DA_) sx[e] = x[e];
        __syncthreads();
        float acc = 0.f;
        #pragma unroll 8
        for (int e = 0; e < DT_; ++e) acc += sx[e] * Wt[e * DA_ + d];
        pt[blk * DA_ + d] = acc;
    } else {
        int r = blk - B_ * I_;
        const float* x = mel + r * DM_;
        if (d < DM_) sx[d] = x[d];
        __syncthreads();
        float acc = bm[d];
        #pragma unroll 8
        for (int e = 0; e < DM_; ++e) acc += sx[e] * Wm[e * DA_ + d];
        pm[r * DA_ + d] = acc;
    }
}

// ---------------- K2: energy + rev-cum -> interleaved EZ[b,i][2j]={E,Z} ----
__global__ __launch_bounds__(384) void energy_kernel(
        const float* __restrict__ pt, const float* __restrict__ pm,
        const float* __restrict__ vw, const float* __restrict__ vb,
        const float* __restrict__ noise, float* __restrict__ EZ) {
    int bi = blockIdx.x;            // b*I + i
    int b = bi / I_, i = bi % I_;
    int t = threadIdx.x;            // j
    int w = t >> 6, lane = t & 63;
    __shared__ float sPt[DA_];
    __shared__ float sPR[8];
    __shared__ float sLast;
    if (t < DA_) sPt[t] = pt[bi * DA_ + t];
    __syncthreads();
    const float4* pmr4 = (const float4*)(pm + (size_t)(b * J_ + t) * DA_);
    float acc = 0.f;
    #pragma unroll 8
    for (int q = 0; q < DA_ / 4; ++q) {
        float4 v = pmr4[q];
        acc += vw[4 * q + 0] * tanh_fast(sPt[4 * q + 0] + v.x);
        acc += vw[4 * q + 1] * tanh_fast(sPt[4 * q + 1] + v.y);
        acc += vw[4 * q + 2] * tanh_fast(sPt[4 * q + 2] + v.z);
        acc += vw[4 * q + 3] * tanh_fast(sPt[4 * q + 3] + v.w);
    }
    float e = (acc + vb[0] + 2.0f * noise[bi * J_ + t]) * LOG2E;   // log2 domain

    float y = wave_scan_rev(e, lane);
    if (lane == 0) sPR[w] = y;
    if (t == J_ - 1) sLast = e;
    __syncthreads();
    float preR = NEG;
    #pragma unroll
    for (int ww = 1; ww < 6; ++ww) if (ww > w) preR = lse2(preR, sPR[ww]);
    float z = lse2(y, preR);
    if (i == I_ - 1) z = sLast;     // last text row: only j=J-1 valid
    float2 o; o.x = e; o.y = z;
    ((float2*)(EZ + (size_t)bi * J_ * 2))[t] = o;
}

// ---------------- K3: banded DP — rolled ping-pong asm pipeline ------------
// Forward-scan only: the reference's "invalid" branch is LOGEPS2 (~-1442 log2)
// below the valid branch for every in-band j (k=i-1 is always in the previous
// band), so it contributes exactly 0 at f32 and is dropped.
// Per body: exactly 3 asm loads (row i+1) + 2 asm stores (row i).
// Counted waits: steady vmcnt(7); prologue 3/5 (derivation in session notes).
#define WAITV_(n) asm volatile("s_waitcnt vmcnt(" #n ")" ::: "memory")
#define WAITV(n) do { WAITV_(n); __builtin_amdgcn_sched_barrier(0); } while (0)

#define LOAD3(S, rowexpr) do { \
    const float* _a = EZb + (size_t)(rowexpr) * (2 * J_) + t * 12; \
    asm volatile("global_load_dwordx4 %0, %3, off\n\t" \
                 "global_load_dwordx4 %1, %3, off offset:16\n\t" \
                 "global_load_dwordx4 %2, %3, off offset:32" \
                 : "=&v"(S##0), "=&v"(S##1), "=&v"(S##2) \
                 : "v"(_a) : "memory"); } while (0)

#define STORE42(addr, q, dd) \
    asm volatile("global_store_dwordx4 %2, %0, off\n\t" \
                 "global_store_dwordx2 %2, %1, off offset:16" \
                 :: "v"(q), "v"(dd), "v"(addr) : "memory")

#define BODY(iexpr, NW, S, DOLOAD, lrow) do { \
    const int i_ = (iexpr); \
    WAITV(NW); \
    float e0 = S##0[0], z0 = S##0[1], e1 = S##0[2], z1 = S##0[3]; \
    float e2 = S##1[0], z2 = S##1[1], e3 = S##1[2], z3 = S##1[3]; \
    float e4 = S##2[0], z4 = S##2[1], e5 = S##2[2], z5 = S##2[3]; \
    if (DOLOAD) LOAD3(S, lrow); \
    float D0 = prev[0] - z0, D1 = prev[1] - z1, D2 = prev[2] - z2; \
    float D3 = prev[3] - z3, D4 = prev[4] - z4, D5 = prev[5] - z5; \
    float s01 = lse2(D0, D1), p23 = lse2(D2, D3), p45 = lse2(D4, D5); \
    float f2 = lse2(s01, D2), f3 = lse2(s01, p23); \
    float f4 = lse2(f3, D4),  f5 = lse2(f3, p45); \
    float Sf  = wave_scan_fwd(f5); \
    float exF = dppf<0x138, 0xF>(Sf);      /* lane t-1 inclusive total */ \
    float eP  = dppf<0x138, 0xF>(e5);      /* lane t-1's e5 = E[p0-1] */ \
    float v0 = eP + exF; \
    float v1 = e0 + lse2(D0,  exF); \
    float v2 = e1 + lse2(s01, exF); \
    float v3 = e2 + lse2(f2,  exF); \
    float v4 = e3 + lse2(f3,  exF); \
    float v5 = e4 + lse2(f4,  exF); \
    int lo = i_, hi = i_ + WIDTH_; \
    prev[0] = (p0 + 0 >= lo && p0 + 0 < hi) ? v0 : NEG; \
    prev[1] = (p0 + 1 >= lo && p0 + 1 < hi) ? v1 : NEG; \
    prev[2] = (p0 + 2 >= lo && p0 + 2 < hi) ? v2 : NEG; \
    prev[3] = (p0 + 3 >= lo && p0 + 3 < hi) ? v3 : NEG; \
    prev[4] = (p0 + 4 >= lo && p0 + 4 < hi) ? v4 : NEG; \
    prev[5] = (p0 + 5 >= lo && p0 + 5 < hi) ? v5 : NEG; \
    { f32x4 q = {prev[0], prev[1], prev[2], prev[3]}; \
      f32x2 dd = {prev[4], prev[5]}; \
      float* _ba = Bb + i_ * J_ + p0; \
      STORE42(_ba, q, dd); } \
} while (0)

__global__ __launch_bounds__(64) void dp_kernel(
        const float* __restrict__ EZ, float* __restrict__ Bij) {
    int b = blockIdx.x;
    int t = threadIdx.x;            // 64 lanes, VPT=6 contiguous positions each
    int p0 = t * VPT;
    const float* EZb = EZ + (size_t)b * I_ * J_ * 2;
    float* Bb = Bij + b * I_ * J_;

    float prev[VPT];
    #pragma unroll
    for (int r = 0; r < VPT; ++r) prev[r] = (p0 + r == 0) ? 0.f : NEG;

    // row 0 store (asm; issued before any LOAD3 so wait counts are unaffected)
    { f32x4 q = {prev[0], prev[1], prev[2], prev[3]};
      f32x2 dd = {prev[4], prev[5]};
      float* _ba = Bb + p0;
      STORE42(_ba, q, dd); }

    f32x4 A0, A1, A2, B0, B1, B2;
    LOAD3(A, 0); LOAD3(B, 1);

    BODY(1, 3, A, 1, 2);            // consume row 0, prefetch row 2
    BODY(2, 5, B, 1, 3);            // consume row 1, prefetch row 3
    #pragma unroll 1
    for (int i = 3; i <= 45; i += 2) {
        BODY(i,     7, A, 1, i + 1);
        BODY(i + 1, 7, B, 1, i + 2);   // i=45: prefetch row 47 (exists; unused)
    }
    BODY(47, 7, A, 0, 0);           // consume row 46
}

// ---------------- K4: soft[b,i,j] — one barrier, register scans ------------
__global__ __launch_bounds__(384) void soft_kernel(
        const float* __restrict__ Bij, const float* __restrict__ EZ,
        float* __restrict__ soft) {
    int bi = blockIdx.x;
    int i = bi % I_;
    int t = threadIdx.x;
    int w = t >> 6, lane = t & 63;
    __shared__ float sPF[8], sPR[8];
    float bv = Bij[bi * J_ + t];
    float2 ez = ((const float2*)(EZ + (size_t)bi * J_ * 2))[t];
    float zz = ez.y;

    float xf = wave_scan_fwd(bv - zz);       // fwd scan of (B - ZZ)
    float yr = wave_scan_rev(bv, lane);      // rev scan of B
    if (lane == 63) sPF[w] = xf;
    if (lane == 0)  sPR[w] = yr;
    __syncthreads();
    float preF = NEG, preR = NEG;
    #pragma unroll
    for (int ww = 0; ww < 5; ++ww) if (ww < w) preF = lse2(preF, sPF[ww]);
    #pragma unroll
    for (int ww = 1; ww < 6; ++ww) if (ww > w) preR = lse2(preR, sPR[ww]);

    float v;
    if (i < I_ - 1) {
        float cum   = lse2(xf, preF);                       // LSE_{k<=j}(B-ZZ)
        float revp1 = lse2(dppf<0x130, 0xF>(yr), preR);     // LSE_{k>j}(B)
        v = lse2(zz + cum, revp1 + LOGEPS2);
    } else {
        float tot = lse2(lse2(lse2(sPR[0], sPR[1]), lse2(sPR[2], sPR[3])),
                         lse2(sPR[4], sPR[5]));             // LSE_k B[last,k]
        v = (t == J_ - 1) ? tot : tot + LOGEPS2;
    }
    soft[bi * J_ + t] = v * LN2;            // back to natural log
}

// ---------------- K5: expanded[b,j,d] = sum_i exp(soft[b,i,j]) * text[b,i,d]
__global__ __launch_bounds__(512) void expand_kernel(
        const float* __restrict__ soft, const float* __restrict__ text,
        float* __restrict__ out) {
    int bj = blockIdx.x;
    int b = bj / J_, j = bj % J_;
    int d = threadIdx.x;
    __shared__ float p[I_];
    if (d < I_) p[d] = __expf(soft[(b * I_ + d) * J_ + j]);
    __syncthreads();
    float acc = 0.f;
    #pragma unroll
    for (int i = 0; i < I_; ++i) acc += p[i] * text[(b * I_ + i) * DT_ + d];
    out[bj * DT_ + d] = acc;
}

extern "C" void kernel_launch(void* const* d_in, const int* in_sizes, int n_in,
                              void* d_out, int out_size, void* d_ws, size_t ws_size,
                              hipStream_t stream) {
    const float* text  = (const float*)d_in[0];
    const float* mel   = (const float*)d_in[1];
    const float* noise = (const float*)d_in[2];
    const float* Wt    = (const float*)d_in[3];
    const float* Wm    = (const float*)d_in[4];
    const float* bm    = (const float*)d_in[5];
    const float* vw    = (const float*)d_in[6];
    const float* vb    = (const float*)d_in[7];
    // masks (d_in[8], d_in[9]) are all-true in this problem: tlen=I, mlen=J hardcoded.

    float* ws  = (float*)d_ws;
    float* EZ  = ws;                         // B*I*J*2 (interleaved E,Z; 16B aligned)
    float* pt  = EZ + B_ * I_ * J_ * 2;      // B*I*DA
    float* pm  = pt + B_ * I_ * DA_;         // B*J*DA
    float* Bij = pm + B_ * J_ * DA_;         // B*I*J   (log2 domain)

    float* soft     = (float*)d_out;             // B*I*J   (natural log)
    float* expanded = soft + B_ * I_ * J_;       // B*J*DT

    proj_kernel<<<B_ * (I_ + J_), 128, 0, stream>>>(text, mel, Wt, Wm, bm, pt, pm);
    energy_kernel<<<B_ * I_, 384, 0, stream>>>(pt, pm, vw, vb, noise, EZ);
    dp_kernel<<<B_, 64, 0, stream>>>(EZ, Bij);
    soft_kernel<<<B_ * I_, 384, 0, stream>>>(Bij, EZ, soft);
    expand_kernel<<<B_ * J_, 512, 0, stream>>>(soft, text, expanded);
}